// Round 3
// baseline (352.359 us; speedup 1.0000x reference)
//
#include <hip/hip_runtime.h>
#include <cstdint>
#include <cstddef>

#define N_NODES 12288
#define IN_F 256
#define OUT_F 128
#define BM 48
#define BK 256
#define NSTEPS (N_NODES / BK)   /* 48 */
#define SLOT_BYTES (BM * BK * 4) /* 48 KB */

using short8 = __attribute__((ext_vector_type(8))) short;
using f32x4  = __attribute__((ext_vector_type(4))) float;

__device__ inline unsigned int cvt_pk_bf16(float lo, float hi) {
  unsigned int r;
  asm volatile("v_cvt_pk_bf16_f32 %0, %1, %2" : "=v"(r) : "v"(lo), "v"(hi));
  return r;
}

__device__ inline unsigned short f2bf(float f) {
  unsigned int u = __float_as_uint(f);
  u = (u + 0x7FFFu + ((u >> 16) & 1u)) >> 16;
  return (unsigned short)u;
}

// ---------------------------------------------------------------- deg pass
__global__ __launch_bounds__(256) void k_deg(const float* __restrict__ adj,
                                             float* __restrict__ dinv) {
  const size_t row = blockIdx.x;
  const float4* p = reinterpret_cast<const float4*>(adj + row * N_NODES) + threadIdx.x;
  float s = 0.f;
#pragma unroll
  for (int i = 0; i < (N_NODES / 4) / 256; ++i) {
    float4 v = p[(size_t)i * 256];
    s += (v.x + v.y) + (v.z + v.w);
  }
#pragma unroll
  for (int off = 32; off >= 1; off >>= 1) s += __shfl_down(s, off, 64);
  __shared__ float red[4];
  const int lane = threadIdx.x & 63, w = threadIdx.x >> 6;
  if (lane == 0) red[w] = s;
  __syncthreads();
  if (threadIdx.x == 0) {
    float tot = (red[0] + red[1]) + (red[2] + red[3]) + 1.0f;
    dinv[row] = rsqrtf(tot);
  }
}

// ------------------------------------------------------------- support pass
__global__ __launch_bounds__(256) void k_support(const float* __restrict__ x,
                                                 const float* __restrict__ W,
                                                 const float* __restrict__ dinv,
                                                 float* __restrict__ ssc,
                                                 unsigned short* __restrict__ sT) {
  const int r = threadIdx.x >> 5;            // 0..7
  const int c4 = (threadIdx.x & 31) << 2;    // 0..124
  const size_t row = (size_t)blockIdx.x * 8 + r;
  const float* xr = x + row * IN_F;
  float a0 = 0.f, a1 = 0.f, a2 = 0.f, a3 = 0.f;
#pragma unroll 4
  for (int k = 0; k < IN_F; ++k) {
    float xv = xr[k];
    float4 wv = *reinterpret_cast<const float4*>(W + (size_t)k * OUT_F + c4);
    a0 = fmaf(xv, wv.x, a0); a1 = fmaf(xv, wv.y, a1);
    a2 = fmaf(xv, wv.z, a2); a3 = fmaf(xv, wv.w, a3);
  }
  const float d = dinv[row];
  a0 *= d; a1 *= d; a2 *= d; a3 *= d;
  *reinterpret_cast<float4*>(ssc + row * OUT_F + c4) = make_float4(a0, a1, a2, a3);
  sT[(size_t)(c4 + 0) * N_NODES + row] = f2bf(a0);
  sT[(size_t)(c4 + 1) * N_NODES + row] = f2bf(a1);
  sT[(size_t)(c4 + 2) * N_NODES + row] = f2bf(a2);
  sT[(size_t)(c4 + 3) * N_NODES + row] = f2bf(a3);
}

// ----------------------------------------------------------------- big GEMM
// out[i][o] = dinv[i]*( sum_j adj[i][j]*sT[o][j] + ssc[i][o] ) + b[o]
// BM=48 rows/block, N=128, BK=256 (1 KB/row/step -> large DRAM bursts).
// A: 3-slot LDS ring (48 KB each), staged 2 steps ahead via global_load_lds.
//    Per wave: 12 instrs, one row each; LDS dest lane-linear (1 KB row),
//    global source XOR-preswizzled (chunk ^ (row&7)) to kill read conflicts.
// B: register prefetch 1 step ahead from L2/L3-resident sT.
__global__ __launch_bounds__(256, 1) void k_gemm(const float* __restrict__ adj,
                                                 const unsigned short* __restrict__ sT,
                                                 const float* __restrict__ ssc,
                                                 const float* __restrict__ dinv,
                                                 const float* __restrict__ bias,
                                                 float* __restrict__ out) {
  __shared__ float As[3][BM * BK];   // 3 x 48 KB = 144 KB

  const int tid = threadIdx.x;
  const int lane = tid & 63;
  const int wv = tid >> 6;
  const size_t rowbase = (size_t)blockIdx.x * BM;

  const int g = lane >> 4;       // k-group 0..3
  const int c15 = lane & 15;     // row-in-16 / B-col-in-16
  const int dr = c15 & 7;        // read-side XOR key (row&7, mt*16 drops out)
  const unsigned short* bptr = sT + (size_t)(wv * 32 + c15) * N_NODES + g * 8;

  f32x4 acc[3][2];
#pragma unroll
  for (int mt = 0; mt < 3; ++mt)
#pragma unroll
    for (int nt = 0; nt < 2; ++nt) acc[mt][nt] = (f32x4){0.f, 0.f, 0.f, 0.f};

  short8 bA[2][8], bB[2][8];  // [nt][kt] ping-pong B sets (128 VGPRs)

  // stage step s into ring slot at byte offset `ob`:
  // wave w covers rows w*12 .. w*12+11, one global_load_lds per row.
  auto stageA = [&](int s, int ob) {
    char* lds0 = (char*)&As[0][0] + ob + lane * 16;
#pragma unroll
    for (int j = 0; j < 12; ++j) {
      const int r = wv * 12 + j;
      const float* src = adj + (rowbase + r) * (size_t)N_NODES + (size_t)s * BK +
                         ((lane ^ (r & 7)) << 2);
      __builtin_amdgcn_global_load_lds(
          (__attribute__((address_space(1))) void*)src,
          (__attribute__((address_space(3))) void*)(lds0 + r * 1024), 16, 0, 0);
    }
  };
  auto loadB = [&](int s, short8 (&B)[2][8]) {
#pragma unroll
    for (int nt = 0; nt < 2; ++nt)
#pragma unroll
      for (int kt = 0; kt < 8; ++kt)
        B[nt][kt] = *(const short8*)(bptr + (size_t)nt * 16 * N_NODES +
                                     (size_t)s * BK + kt * 32);
  };
  auto compute = [&](int ob, short8 (&B)[2][8]) {
    const char* Ab = (const char*)&As[0][0] + ob;
#pragma unroll
    for (int mt = 0; mt < 3; ++mt) {
      const int rowoff = mt * 16384 + c15 * 1024;
#pragma unroll
      for (int kt = 0; kt < 8; ++kt) {
        const int cbase = kt * 8 + g * 2;
        f32x4 lo = *(const f32x4*)(Ab + rowoff + ((cbase ^ dr) << 4));
        f32x4 hi = *(const f32x4*)(Ab + rowoff + (((cbase + 1) ^ dr) << 4));
        union { unsigned int u[4]; short8 v; } t;
        t.u[0] = cvt_pk_bf16(lo[0], lo[1]);
        t.u[1] = cvt_pk_bf16(lo[2], lo[3]);
        t.u[2] = cvt_pk_bf16(hi[0], hi[1]);
        t.u[3] = cvt_pk_bf16(hi[2], hi[3]);
#pragma unroll
        for (int nt = 0; nt < 2; ++nt)
          acc[mt][nt] = __builtin_amdgcn_mfma_f32_16x16x32_bf16(
              t.v, B[nt][kt], acc[mt][nt], 0, 0, 0);
      }
    }
  };

  int o0 = 0, o1 = SLOT_BYTES, o2 = 2 * SLOT_BYTES;  // slots for s, s+1, s+2

// Steady state per wave per step: issue B(s+1)[16] then A(s+2)[12];
// newer-than-B(s) = A(s+1)12 + B(s+1)16 + A(s+2)12 = 40.
#define GSTEP(s, CUR, NXT, DOSTAGE, DOLOADB, VMC)                \
  {                                                              \
    if (DOLOADB) loadB((s) + 1, NXT);                            \
    __builtin_amdgcn_sched_barrier(0);                           \
    if (DOSTAGE) stageA((s) + 2, o2);                            \
    __builtin_amdgcn_sched_barrier(0);                           \
    asm volatile("s_waitcnt vmcnt(" VMC ")" ::: "memory");       \
    __builtin_amdgcn_s_barrier();                                \
    __builtin_amdgcn_sched_barrier(0);                           \
    compute(o0, CUR);                                            \
    int tmp = o0; o0 = o1; o1 = o2; o2 = tmp;                    \
  }

  // prologue: A(0), B(0), A(1) — order pinned for the vmcnt count
  stageA(0, o0);
  __builtin_amdgcn_sched_barrier(0);
  loadB(0, bA);
  __builtin_amdgcn_sched_barrier(0);
  stageA(1, o1);

  for (int s = 0; s < NSTEPS - 2; s += 2) {
    GSTEP(s, bA, bB, 1, 1, "40");
    GSTEP(s + 1, bB, bA, 1, 1, "40");
  }
  // s=46: no stage; newer-than-B(46) = A(47)12 + B(47)16 = 28
  GSTEP(NSTEPS - 2, bA, bB, 0, 1, "28");
  GSTEP(NSTEPS - 1, bB, bA, 0, 0, "0");
#undef GSTEP

  // epilogue: C/D layout col=lane&15, row=(lane>>4)*4+r
  const int col0 = wv * 32 + c15;
#pragma unroll
  for (int mt = 0; mt < 3; ++mt) {
#pragma unroll
    for (int nt = 0; nt < 2; ++nt) {
      const int col = col0 + nt * 16;
      const float bv = bias[col];
#pragma unroll
      for (int r = 0; r < 4; ++r) {
        const size_t orow = rowbase + mt * 16 + (g << 2) + r;
        const float d = dinv[orow];
        out[orow * OUT_F + col] =
            fmaf(d, acc[mt][nt][r] + ssc[orow * OUT_F + col], bv);
      }
    }
  }
}

extern "C" void kernel_launch(void* const* d_in, const int* in_sizes, int n_in,
                              void* d_out, int out_size, void* d_ws, size_t ws_size,
                              hipStream_t stream) {
  const float* x   = (const float*)d_in[0];
  const float* adj = (const float*)d_in[1];
  const float* W   = (const float*)d_in[2];
  const float* b   = (const float*)d_in[3];
  float* out = (float*)d_out;

  // workspace layout (bytes): dinv 48K | ssc 6.0M | sT 3.0M  (~9.5 MB)
  char* ws = (char*)d_ws;
  float* dinv        = (float*)ws;
  float* ssc         = (float*)(ws + 49152);
  unsigned short* sT = (unsigned short*)(ws + 49152 + 6291456);

  k_deg<<<N_NODES, 256, 0, stream>>>(adj, dinv);
  k_support<<<N_NODES / 8, 256, 0, stream>>>(x, W, dinv, ssc, sT);
  k_gemm<<<256, 256, 0, stream>>>(adj, sT, ssc, dinv, b, out);
}

// Round 4
// 343.314 us; speedup vs baseline: 1.0263x; 1.0263x over previous
//
#include <hip/hip_runtime.h>
#include <cstdint>
#include <cstddef>

#define N_NODES 12288
#define IN_F 256
#define OUT_F 128
#define BM 48
#define BK 256
#define NSTEPS (N_NODES / BK)   /* 48 */
#define SLOT_BYTES (BM * BK * 4) /* 48 KB */

using short8 = __attribute__((ext_vector_type(8))) short;
using f32x4  = __attribute__((ext_vector_type(4))) float;

__device__ inline unsigned int cvt_pk_bf16(float lo, float hi) {
  unsigned int r;
  asm volatile("v_cvt_pk_bf16_f32 %0, %1, %2" : "=v"(r) : "v"(lo), "v"(hi));
  return r;
}

__device__ inline unsigned short f2bf(float f) {
  unsigned int u = __float_as_uint(f);
  u = (u + 0x7FFFu + ((u >> 16) & 1u)) >> 16;
  return (unsigned short)u;
}

// ---------------------------------------------------------------- deg pass
// dinv[i] = rsqrt(1 + sum_j adj[i][j]). Chunk sweep start rotated by row so
// co-resident blocks are not all reading the same column phase.
__global__ __launch_bounds__(256) void k_deg(const float* __restrict__ adj,
                                             float* __restrict__ dinv) {
  const size_t row = blockIdx.x;
  const float4* p = reinterpret_cast<const float4*>(adj + row * N_NODES) + threadIdx.x;
  const int start = (int)(row % 12);
  float s = 0.f;
#pragma unroll
  for (int i = 0; i < 12; ++i) {
    int idx = i + start; if (idx >= 12) idx -= 12;
    float4 v = p[(size_t)idx * 256];
    s += (v.x + v.y) + (v.z + v.w);
  }
#pragma unroll
  for (int off = 32; off >= 1; off >>= 1) s += __shfl_down(s, off, 64);
  __shared__ float red[4];
  const int lane = threadIdx.x & 63, w = threadIdx.x >> 6;
  if (lane == 0) red[w] = s;
  __syncthreads();
  if (threadIdx.x == 0) {
    float tot = (red[0] + red[1]) + (red[2] + red[3]) + 1.0f;
    dinv[row] = rsqrtf(tot);
  }
}

// ------------------------------------------------------------- support pass
__global__ __launch_bounds__(256) void k_support(const float* __restrict__ x,
                                                 const float* __restrict__ W,
                                                 const float* __restrict__ dinv,
                                                 float* __restrict__ ssc,
                                                 unsigned short* __restrict__ sT) {
  const int r = threadIdx.x >> 5;            // 0..7
  const int c4 = (threadIdx.x & 31) << 2;    // 0..124
  const size_t row = (size_t)blockIdx.x * 8 + r;
  const float* xr = x + row * IN_F;
  float a0 = 0.f, a1 = 0.f, a2 = 0.f, a3 = 0.f;
#pragma unroll 4
  for (int k = 0; k < IN_F; ++k) {
    float xv = xr[k];
    float4 wv = *reinterpret_cast<const float4*>(W + (size_t)k * OUT_F + c4);
    a0 = fmaf(xv, wv.x, a0); a1 = fmaf(xv, wv.y, a1);
    a2 = fmaf(xv, wv.z, a2); a3 = fmaf(xv, wv.w, a3);
  }
  const float d = dinv[row];
  a0 *= d; a1 *= d; a2 *= d; a3 *= d;
  *reinterpret_cast<float4*>(ssc + row * OUT_F + c4) = make_float4(a0, a1, a2, a3);
  sT[(size_t)(c4 + 0) * N_NODES + row] = f2bf(a0);
  sT[(size_t)(c4 + 1) * N_NODES + row] = f2bf(a1);
  sT[(size_t)(c4 + 2) * N_NODES + row] = f2bf(a2);
  sT[(size_t)(c4 + 3) * N_NODES + row] = f2bf(a3);
}

// ----------------------------------------------------------------- big GEMM
// out[i][o] = dinv[i]*( sum_j adj[i][j]*sT[o][j] + ssc[i][o] ) + b[o]
// Same structure as R3 (BM=48, BK=256, 3-slot LDS ring, counted vmcnt),
// plus per-block K-phase stagger: block b sweeps columns starting at
// phase (b % NSTEPS), wrapping. De-correlates DRAM channel/bank phases
// across co-resident blocks (the invariant shared by all prior nulls).
__global__ __launch_bounds__(256, 1) void k_gemm(const float* __restrict__ adj,
                                                 const unsigned short* __restrict__ sT,
                                                 const float* __restrict__ ssc,
                                                 const float* __restrict__ dinv,
                                                 const float* __restrict__ bias,
                                                 float* __restrict__ out) {
  __shared__ float As[3][BM * BK];   // 3 x 48 KB = 144 KB

  const int tid = threadIdx.x;
  const int lane = tid & 63;
  const int wv = tid >> 6;
  const size_t rowbase = (size_t)blockIdx.x * BM;
  const int ph = blockIdx.x % NSTEPS;

  const int g = lane >> 4;       // k-group 0..3
  const int c15 = lane & 15;     // row-in-16 / B-col-in-16
  const int dr = c15 & 7;        // read-side XOR key
  const unsigned short* bptr = sT + (size_t)(wv * 32 + c15) * N_NODES + g * 8;

  f32x4 acc[3][2];
#pragma unroll
  for (int mt = 0; mt < 3; ++mt)
#pragma unroll
    for (int nt = 0; nt < 2; ++nt) acc[mt][nt] = (f32x4){0.f, 0.f, 0.f, 0.f};

  short8 bA[2][8], bB[2][8];  // [nt][kt] ping-pong B sets

  // logical step t -> physical column step (t + ph) mod NSTEPS
  auto phys = [&](int t) { int c = t + ph; if (c >= NSTEPS) c -= NSTEPS; return c; };

  auto stageA = [&](int t, int ob) {
    const int sc = phys(t);
    char* lds0 = (char*)&As[0][0] + ob + lane * 16;
#pragma unroll
    for (int j = 0; j < 12; ++j) {
      const int r = wv * 12 + j;
      const float* src = adj + (rowbase + r) * (size_t)N_NODES + (size_t)sc * BK +
                         ((lane ^ (r & 7)) << 2);
      __builtin_amdgcn_global_load_lds(
          (__attribute__((address_space(1))) void*)src,
          (__attribute__((address_space(3))) void*)(lds0 + r * 1024), 16, 0, 0);
    }
  };
  auto loadB = [&](int t, short8 (&B)[2][8]) {
    const int sc = phys(t);
#pragma unroll
    for (int nt = 0; nt < 2; ++nt)
#pragma unroll
      for (int kt = 0; kt < 8; ++kt)
        B[nt][kt] = *(const short8*)(bptr + (size_t)nt * 16 * N_NODES +
                                     (size_t)sc * BK + kt * 32);
  };
  auto compute = [&](int ob, short8 (&B)[2][8]) {
    const char* Ab = (const char*)&As[0][0] + ob;
#pragma unroll
    for (int mt = 0; mt < 3; ++mt) {
      const int rowoff = mt * 16384 + c15 * 1024;
#pragma unroll
      for (int kt = 0; kt < 8; ++kt) {
        const int cbase = kt * 8 + g * 2;
        f32x4 lo = *(const f32x4*)(Ab + rowoff + ((cbase ^ dr) << 4));
        f32x4 hi = *(const f32x4*)(Ab + rowoff + (((cbase + 1) ^ dr) << 4));
        union { unsigned int u[4]; short8 v; } t;
        t.u[0] = cvt_pk_bf16(lo[0], lo[1]);
        t.u[1] = cvt_pk_bf16(lo[2], lo[3]);
        t.u[2] = cvt_pk_bf16(hi[0], hi[1]);
        t.u[3] = cvt_pk_bf16(hi[2], hi[3]);
#pragma unroll
        for (int nt = 0; nt < 2; ++nt)
          acc[mt][nt] = __builtin_amdgcn_mfma_f32_16x16x32_bf16(
              t.v, B[nt][kt], acc[mt][nt], 0, 0, 0);
      }
    }
  };

  int o0 = 0, o1 = SLOT_BYTES, o2 = 2 * SLOT_BYTES;  // slots for s, s+1, s+2

// Steady state per wave per step: issue B(s+1)[16] then A(s+2)[12];
// newer-than-B(s) = A(s+1)12 + B(s+1)16 + A(s+2)12 = 40.
#define GSTEP(s, CUR, NXT, DOSTAGE, DOLOADB, VMC)                \
  {                                                              \
    if (DOLOADB) loadB((s) + 1, NXT);                            \
    __builtin_amdgcn_sched_barrier(0);                           \
    if (DOSTAGE) stageA((s) + 2, o2);                            \
    __builtin_amdgcn_sched_barrier(0);                           \
    asm volatile("s_waitcnt vmcnt(" VMC ")" ::: "memory");       \
    __builtin_amdgcn_s_barrier();                                \
    __builtin_amdgcn_sched_barrier(0);                           \
    compute(o0, CUR);                                            \
    int tmp = o0; o0 = o1; o1 = o2; o2 = tmp;                    \
  }

  // prologue: A(0), B(0), A(1) — order pinned for the vmcnt count
  stageA(0, o0);
  __builtin_amdgcn_sched_barrier(0);
  loadB(0, bA);
  __builtin_amdgcn_sched_barrier(0);
  stageA(1, o1);

  for (int s = 0; s < NSTEPS - 2; s += 2) {
    GSTEP(s, bA, bB, 1, 1, "40");
    GSTEP(s + 1, bB, bA, 1, 1, "40");
  }
  // s=46: no stage; newer-than-B(46) = A(47)12 + B(47)16 = 28
  GSTEP(NSTEPS - 2, bA, bB, 0, 1, "28");
  GSTEP(NSTEPS - 1, bB, bA, 0, 0, "0");
#undef GSTEP

  // epilogue: C/D layout col=lane&15, row=(lane>>4)*4+r
  const int col0 = wv * 32 + c15;
#pragma unroll
  for (int mt = 0; mt < 3; ++mt) {
#pragma unroll
    for (int nt = 0; nt < 2; ++nt) {
      const int col = col0 + nt * 16;
      const float bv = bias[col];
#pragma unroll
      for (int r = 0; r < 4; ++r) {
        const size_t orow = rowbase + mt * 16 + (g << 2) + r;
        const float d = dinv[orow];
        out[orow * OUT_F + col] =
            fmaf(d, acc[mt][nt][r] + ssc[orow * OUT_F + col], bv);
      }
    }
  }
}

extern "C" void kernel_launch(void* const* d_in, const int* in_sizes, int n_in,
                              void* d_out, int out_size, void* d_ws, size_t ws_size,
                              hipStream_t stream) {
  const float* x   = (const float*)d_in[0];
  const float* adj = (const float*)d_in[1];
  const float* W   = (const float*)d_in[2];
  const float* b   = (const float*)d_in[3];
  float* out = (float*)d_out;

  // workspace layout (bytes): dinv 48K | ssc 6.0M | sT 3.0M  (~9.5 MB)
  char* ws = (char*)d_ws;
  float* dinv        = (float*)ws;
  float* ssc         = (float*)(ws + 49152);
  unsigned short* sT = (unsigned short*)(ws + 49152 + 6291456);

  k_deg<<<N_NODES, 256, 0, stream>>>(adj, dinv);
  k_support<<<N_NODES / 8, 256, 0, stream>>>(x, W, dinv, ssc, sT);
  k_gemm<<<256, 256, 0, stream>>>(adj, sT, ssc, dinv, b, out);
}

// Round 5
// 268.285 us; speedup vs baseline: 1.3134x; 1.2797x over previous
//
#include <hip/hip_runtime.h>
#include <cstdint>
#include <cstddef>

#define N_NODES 12288
#define IN_F 256
#define OUT_F 128
#define BM 48
#define BK 256                      /* K elements per step = bytes (fp8) */
#define NSTEPS (N_NODES / BK)       /* 48 */
#define A_BYTES (BM * BK)           /* 12288 */
#define B_BYTES (OUT_F * BK)        /* 32768 */
#define SLOT (A_BYTES + B_BYTES)    /* 45056 */

using f32x4 = __attribute__((ext_vector_type(4))) float;
typedef long long i64;

// ---------------------------------------------------------------- deg pass
// dinv[i] = rsqrt(1 + sum_j adj[i][j]); ALSO writes adjq = e4m3(adj) so the
// GEMM re-reads 151 MB instead of 604 MB.
__global__ __launch_bounds__(256) void k_deg(const float* __restrict__ adj,
                                             float* __restrict__ dinv,
                                             unsigned int* __restrict__ adjq) {
  const size_t row = blockIdx.x;
  const float4* p = reinterpret_cast<const float4*>(adj + row * N_NODES) + threadIdx.x;
  unsigned int* q = adjq + row * (N_NODES / 4) + threadIdx.x;
  float s = 0.f;
#pragma unroll
  for (int i = 0; i < (N_NODES / 4) / 256; ++i) {
    float4 v = p[(size_t)i * 256];
    s += (v.x + v.y) + (v.z + v.w);
    unsigned int u = (unsigned)__builtin_amdgcn_cvt_pk_fp8_f32(v.x, v.y, 0, false);
    u = (unsigned)__builtin_amdgcn_cvt_pk_fp8_f32(v.z, v.w, (int)u, true);
    q[(size_t)i * 256] = u;
  }
#pragma unroll
  for (int off = 32; off >= 1; off >>= 1) s += __shfl_down(s, off, 64);
  __shared__ float red[4];
  const int lane = threadIdx.x & 63, w = threadIdx.x >> 6;
  if (lane == 0) red[w] = s;
  __syncthreads();
  if (threadIdx.x == 0) {
    float tot = (red[0] + red[1]) + (red[2] + red[3]) + 1.0f;
    dinv[row] = rsqrtf(tot);
  }
}

// ------------------------------------------------------------- support pass
// ssc[j][o] = dinv[j]*(x@W)[j][o]  (fp32, exact self-loop path)
// sTq[o][j] = e4m3(64 * ssc[j][o]) (transposed fp8 B; x64 keeps values in
//                                   e4m3 normal range; /64 in GEMM epilogue)
__global__ __launch_bounds__(256) void k_support(const float* __restrict__ x,
                                                 const float* __restrict__ W,
                                                 const float* __restrict__ dinv,
                                                 float* __restrict__ ssc,
                                                 unsigned char* __restrict__ sTq) {
  const int r = threadIdx.x >> 5;            // 0..7
  const int c4 = (threadIdx.x & 31) << 2;    // 0..124
  const size_t row = (size_t)blockIdx.x * 8 + r;
  const float* xr = x + row * IN_F;
  float a0 = 0.f, a1 = 0.f, a2 = 0.f, a3 = 0.f;
#pragma unroll 4
  for (int k = 0; k < IN_F; ++k) {
    float xv = xr[k];
    float4 wv = *reinterpret_cast<const float4*>(W + (size_t)k * OUT_F + c4);
    a0 = fmaf(xv, wv.x, a0); a1 = fmaf(xv, wv.y, a1);
    a2 = fmaf(xv, wv.z, a2); a3 = fmaf(xv, wv.w, a3);
  }
  const float d = dinv[row];
  a0 *= d; a1 *= d; a2 *= d; a3 *= d;
  *reinterpret_cast<float4*>(ssc + row * OUT_F + c4) = make_float4(a0, a1, a2, a3);
  unsigned int u01 = (unsigned)__builtin_amdgcn_cvt_pk_fp8_f32(a0 * 64.f, a1 * 64.f, 0, false);
  unsigned int u23 = (unsigned)__builtin_amdgcn_cvt_pk_fp8_f32(a2 * 64.f, a3 * 64.f, 0, false);
  sTq[(size_t)(c4 + 0) * N_NODES + row] = (unsigned char)(u01 & 0xff);
  sTq[(size_t)(c4 + 1) * N_NODES + row] = (unsigned char)((u01 >> 8) & 0xff);
  sTq[(size_t)(c4 + 2) * N_NODES + row] = (unsigned char)(u23 & 0xff);
  sTq[(size_t)(c4 + 3) * N_NODES + row] = (unsigned char)((u23 >> 8) & 0xff);
}

// ----------------------------------------------------------------- big GEMM
// out[i][o] = dinv[i]*( (1/64) * sum_j adjq[i][j]*sTq[o][j] + ssc[i][o] ) + b[o]
// fp8 A (HBM, 151 MB) and fp8 B (L2-resident) both staged via global_load_lds
// into a 2-slot LDS double buffer with chunk-XOR source pre-swizzle
// (linear dest, swizzled read -> conflict-free ds_read_b64).
// Race-safe order per step: wait+barrier -> compute -> barrier -> stage(s+2).
__global__ __launch_bounds__(256, 1) void k_gemm(const unsigned char* __restrict__ adjq,
                                                 const unsigned char* __restrict__ sTq,
                                                 const float* __restrict__ ssc,
                                                 const float* __restrict__ dinv,
                                                 const float* __restrict__ bias,
                                                 float* __restrict__ out) {
  __shared__ __align__(16) char LDSBUF[2 * SLOT];   // 88 KB

  const int tid = threadIdx.x;
  const int lane = tid & 63;
  const int wv = tid >> 6;
  const size_t rowbase = (size_t)blockIdx.x * BM;

  const int g = lane >> 4;       // k-group 0..3 (also row-within-instr on stage)
  const int c15 = lane & 15;     // fragment row/col within 16
  const int dr = c15 & 7;        // read-side XOR key

  f32x4 acc[3][2];
#pragma unroll
  for (int mt = 0; mt < 3; ++mt)
#pragma unroll
    for (int nt = 0; nt < 2; ++nt) acc[mt][nt] = (f32x4){0.f, 0.f, 0.f, 0.f};

  // Stage step s into slot: A tile 48x256B (12 instrs) + B tile 128x256B
  // (32 instrs); 11 instrs/wave. Source chunk pre-swizzled by dest row&7.
  auto stage = [&](int s, int slot) {
    char* L = LDSBUF + slot * SLOT;
#pragma unroll
    for (int j = 0; j < 3; ++j) {
      const int instr = wv * 3 + j;
      const int r = instr * 4 + g;
      const int chunk = c15 ^ (r & 7);
      const unsigned char* src = adjq + (rowbase + r) * (size_t)N_NODES +
                                 (size_t)s * BK + chunk * 16;
      __builtin_amdgcn_global_load_lds(
          (__attribute__((address_space(1))) void*)src,
          (__attribute__((address_space(3))) void*)(L + instr * 1024 + lane * 16),
          16, 0, 0);
    }
#pragma unroll
    for (int j = 0; j < 8; ++j) {
      const int instr = wv * 8 + j;
      const int o = instr * 4 + g;
      const int chunk = c15 ^ (o & 7);
      const unsigned char* src = sTq + (size_t)o * N_NODES + (size_t)s * BK + chunk * 16;
      __builtin_amdgcn_global_load_lds(
          (__attribute__((address_space(1))) void*)src,
          (__attribute__((address_space(3))) void*)(L + A_BYTES + instr * 1024 + lane * 16),
          16, 0, 0);
    }
  };

  auto compute = [&](int slot) {
    const char* LA = LDSBUF + slot * SLOT;
    const char* LB = LA + A_BYTES;
    const int bcol0 = wv * 32 + c15;
#pragma unroll
    for (int kt = 0; kt < 8; ++kt) {
      // fragment bytes k = kt*32 + g*8 .. +8; physical chunk = logical ^ dr
      const int phys = (((kt * 2 + (g >> 1)) ^ dr) << 4) + ((g & 1) << 3);
      i64 a0 = *(const i64*)(LA + (0 * 16 + c15) * 256 + phys);
      i64 a1 = *(const i64*)(LA + (1 * 16 + c15) * 256 + phys);
      i64 a2 = *(const i64*)(LA + (2 * 16 + c15) * 256 + phys);
      i64 b0 = *(const i64*)(LB + (size_t)(bcol0)*256 + phys);
      i64 b1 = *(const i64*)(LB + (size_t)(bcol0 + 16) * 256 + phys);
      acc[0][0] = __builtin_amdgcn_mfma_f32_16x16x32_fp8_fp8(a0, b0, acc[0][0], 0, 0, 0);
      acc[0][1] = __builtin_amdgcn_mfma_f32_16x16x32_fp8_fp8(a0, b1, acc[0][1], 0, 0, 0);
      acc[1][0] = __builtin_amdgcn_mfma_f32_16x16x32_fp8_fp8(a1, b0, acc[1][0], 0, 0, 0);
      acc[1][1] = __builtin_amdgcn_mfma_f32_16x16x32_fp8_fp8(a1, b1, acc[1][1], 0, 0, 0);
      acc[2][0] = __builtin_amdgcn_mfma_f32_16x16x32_fp8_fp8(a2, b0, acc[2][0], 0, 0, 0);
      acc[2][1] = __builtin_amdgcn_mfma_f32_16x16x32_fp8_fp8(a2, b1, acc[2][1], 0, 0, 0);
    }
  };

// Per step: wait for stage(s) (stage(s+1) outstanding -> vmcnt(11));
// barrier; compute(s); barrier (all waves done reading slot); stage(s+2)
// into the slot just freed. Max outstanding 22 < 63.
#define GSTEP(s, VMC, DOSTAGE)                                   \
  {                                                              \
    asm volatile("s_waitcnt vmcnt(" VMC ")" ::: "memory");       \
    __builtin_amdgcn_s_barrier();                                \
    __builtin_amdgcn_sched_barrier(0);                           \
    compute((s) & 1);                                            \
    __builtin_amdgcn_s_barrier();                                \
    __builtin_amdgcn_sched_barrier(0);                           \
    if (DOSTAGE) stage((s) + 2, (s) & 1);                        \
    __builtin_amdgcn_sched_barrier(0);                           \
  }

  stage(0, 0);
  __builtin_amdgcn_sched_barrier(0);
  stage(1, 1);

  for (int s = 0; s < NSTEPS - 2; ++s) GSTEP(s, "11", 1);
  GSTEP(NSTEPS - 2, "11", 0);
  GSTEP(NSTEPS - 1, "0", 0);
#undef GSTEP

  // epilogue: C/D layout col=lane&15, row=(lane>>4)*4+r
  const float inv64 = 0.015625f;
  const int col0 = wv * 32 + c15;
#pragma unroll
  for (int mt = 0; mt < 3; ++mt) {
#pragma unroll
    for (int nt = 0; nt < 2; ++nt) {
      const int col = col0 + nt * 16;
      const float bv = bias[col];
#pragma unroll
      for (int r = 0; r < 4; ++r) {
        const size_t orow = rowbase + mt * 16 + (g << 2) + r;
        const float d = dinv[orow];
        out[orow * OUT_F + col] =
            fmaf(d, acc[mt][nt][r] * inv64 + ssc[orow * OUT_F + col], bv);
      }
    }
  }
}

extern "C" void kernel_launch(void* const* d_in, const int* in_sizes, int n_in,
                              void* d_out, int out_size, void* d_ws, size_t ws_size,
                              hipStream_t stream) {
  const float* x   = (const float*)d_in[0];
  const float* adj = (const float*)d_in[1];
  const float* W   = (const float*)d_in[2];
  const float* b   = (const float*)d_in[3];
  float* out = (float*)d_out;

  // ws layout: dinv 48K | ssc 6.0M | sTq 1.5M | adjq 151M   (~159 MB)
  char* ws = (char*)d_ws;
  float* dinv         = (float*)ws;
  float* ssc          = (float*)(ws + 49152);
  unsigned char* sTq  = (unsigned char*)(ws + 49152 + 6291456);
  unsigned char* adjq = (unsigned char*)(ws + 49152 + 6291456 + 1572864);

  k_deg<<<N_NODES, 256, 0, stream>>>(adj, dinv, (unsigned int*)adjq);
  k_support<<<N_NODES / 8, 256, 0, stream>>>(x, W, dinv, ssc, sTq);
  k_gemm<<<256, 256, 0, stream>>>(adjq, sTq, ssc, dinv, b, out);
}